// Round 4
// baseline (316.877 us; speedup 1.0000x reference)
//
#include <hip/hip_runtime.h>
#include <stdint.h>

// Sparse strided conv: scatter (features@W1 -> grid) + gather (grid@W2 -> out).
// R4: scatter/gather at 256-thread blocks (4 indep waves/block) -> 32 waves/CU
//     (was 1-wave blocks capped at 16 wg/CU = 60% occ, latency-bound on random
//     grid-row reads). k_zero_grid fused into k_assign (contiguous row range).

#define N_VOX 120000
#define IC 32
#define OC 64
#define NKV 27
#define DZ 21
#define HY 200
#define WX 176
#define TBL_BITS 20
#define TBL_SIZE (1 << TBL_BITS)
#define TBL_MASK (TBL_SIZE - 1)
#define MAXROWS 480000
#define VPW 256                    // voxels scanned per wave
#define VPBLK (VPW * 4)            // per 4-wave block

// ws layout (bytes)
#define OFF_KEYS 0
#define OFF_VALS 4194304
#define OFF_CNT 8388608
#define OFF_ROWS 8388864
#define OFF_GRID 21348864
#define WS_NEEDED (OFF_GRID + (size_t)MAXROWS * OC * 4)

__device__ __forceinline__ uint32_t hash_lin(int lin) {
    return ((uint32_t)lin * 2654435761u) >> (32 - TBL_BITS);
}

__device__ __forceinline__ void atomAddF32(float* p, float v) {
    unsafeAtomicAdd(p, v);  // global_atomic_add_f32 on gfx950
}

__global__ void k_init(int* keys, float* out, int* counter) {
    int i = blockIdx.x * blockDim.x + threadIdx.x;
    int stride = gridDim.x * blockDim.x;
    for (int j = i; j < N_VOX * IC; j += stride) out[j] = 0.f;
    for (int j = i; j < TBL_SIZE; j += stride) keys[j] = -1;
    if (i == 0) *counter = 0;
}

__global__ void k_build(const int* __restrict__ coors, int* keys, int* rows) {
    int v = blockIdx.x * blockDim.x + threadIdx.x;
    if (v >= N_VOX) return;
    int b = coors[v * 4 + 0];
    int z = coors[v * 4 + 1];
    int y = coors[v * 4 + 2];
    int x = coors[v * 4 + 3];
#pragma unroll
    for (int kv = 0; kv < NKV; ++kv) {
        int oz = kv / 9, oy = (kv / 3) % 3, ox = kv % 3;
        int az = z + 1 - oz, ay = y + 1 - oy, ax = x + 1 - ox;
        int slot = -1;
        bool valid = (az >= 0) && !(az & 1) && ((az >> 1) < DZ) &&
                     (ay >= 0) && !(ay & 1) && ((ay >> 1) < HY) &&
                     (ax >= 0) && !(ax & 1) && ((ax >> 1) < WX);
        if (valid) {
            int lin = ((b * DZ + (az >> 1)) * HY + (ay >> 1)) * WX + (ax >> 1);
            uint32_t h = hash_lin(lin);
            for (;;) {
                int k = atomicCAS(&keys[h], -1, lin);
                if (k == -1 || k == lin) { slot = (int)h; break; }
                h = (h + 1) & TBL_MASK;
            }
        }
        rows[kv * N_VOX + v] = slot;
    }
}

// Block-aggregated compaction (1 atomic/block) + fused zeroing of the block's
// contiguous claimed row range [base, base+total).
__global__ __launch_bounds__(256) void k_assign(const int* __restrict__ keys,
                                                int* __restrict__ vals,
                                                int* counter,
                                                float4* __restrict__ gridc4) {
    const int t = threadIdx.x;
    const int s0 = blockIdx.x * 2048 + t * 8;
    const int4 a = ((const int4*)(keys + s0))[0];
    const int4 b = ((const int4*)(keys + s0))[1];
    int k[8] = {a.x, a.y, a.z, a.w, b.x, b.y, b.z, b.w};
    int c = 0;
#pragma unroll
    for (int i = 0; i < 8; ++i) c += (k[i] != -1);

    __shared__ int sc[256];
    __shared__ int base;
    sc[t] = c;
    __syncthreads();
#pragma unroll
    for (int d = 1; d < 256; d <<= 1) {
        int y = (t >= d) ? sc[t - d] : 0;
        __syncthreads();
        sc[t] += y;
        __syncthreads();
    }
    if (t == 255) base = atomicAdd(counter, sc[255]);
    __syncthreads();
    const int total = sc[255];
    int r = base + sc[t] - c;  // exclusive prefix
#pragma unroll
    for (int i = 0; i < 8; ++i) {
        if (k[i] != -1) { vals[s0 + i] = (r < MAXROWS) ? r : -1; ++r; }
    }
    // fused grid zero: rows [base, base+total) are this block's, contiguous.
    int zs = min(base, MAXROWS), ze = min(base + total, MAXROWS);
    float4 zz = {0.f, 0.f, 0.f, 0.f};
    for (int i = zs * 16 + t; i < ze * 16; i += 256) gridc4[i] = zz;
}

__global__ void k_rows_fix(int* rows, const int* __restrict__ vals) {
    int i = blockIdx.x * blockDim.x + threadIdx.x;
    if (i >= NKV * N_VOX) return;
    int s = rows[i];
    rows[i] = (s >= 0) ? vals[s] : -1;
}

// Ballot-compact valid (v,row) pairs of this wave's VPW voxels into its LDS
// region. One wave only -> no barrier needed.
__device__ __forceinline__ int compact_pairs(const int* __restrict__ rkv,
                                             int v0, int lane, int2* ls) {
    int n = 0;
#pragma unroll
    for (int ch = 0; ch < VPW / 64; ++ch) {
        int v = v0 + ch * 64 + lane;
        int row = (v < N_VOX) ? rkv[v] : -1;
        unsigned long long m = __ballot(row >= 0);
        int pos = n + (int)__popcll(m & ((1ULL << lane) - 1));
        if (row >= 0) ls[pos] = make_int2(v, row);
        n += (int)__popcll(m);
    }
    return n;
}

// 4 independent waves per block; wave = VPW voxels of one kv.
// lane = output channel o. W1[kv] column in 32 VGPRs.
__global__ __launch_bounds__(256) void k_scatter(const float* __restrict__ feat,
                                                 const float* __restrict__ W1,
                                                 const int* __restrict__ rows,
                                                 float* gridc) {
    const int kv = blockIdx.y;
    const int wid = threadIdx.x >> 6;
    const int lane = threadIdx.x & 63;
    __shared__ int2 ls[4][VPW];

    float w[IC];
#pragma unroll
    for (int c = 0; c < IC; ++c) w[c] = W1[(kv * IC + c) * OC + lane];

    const int v0 = (blockIdx.x * 4 + wid) * VPW;
    const int n = (v0 < N_VOX)
                      ? compact_pairs(rows + kv * N_VOX, v0, lane, ls[wid])
                      : 0;

    for (int p = 0; p < n; p += 2) {
        const bool hasB = (p + 1 < n);
        const int2 A = ls[wid][p];
        const int2 B = ls[wid][hasB ? p + 1 : p];
        const float4* pA = (const float4*)(feat + (size_t)A.x * IC);
        const float4* pB = (const float4*)(feat + (size_t)B.x * IC);
        float4 fA[8], fB[8];
#pragma unroll
        for (int j = 0; j < 8; ++j) { fA[j] = pA[j]; fB[j] = pB[j]; }
        float accA = 0.f, accB = 0.f;
#pragma unroll
        for (int j = 0; j < 8; ++j) {
            accA = fmaf(fA[j].x, w[4 * j + 0], accA);
            accA = fmaf(fA[j].y, w[4 * j + 1], accA);
            accA = fmaf(fA[j].z, w[4 * j + 2], accA);
            accA = fmaf(fA[j].w, w[4 * j + 3], accA);
            accB = fmaf(fB[j].x, w[4 * j + 0], accB);
            accB = fmaf(fB[j].y, w[4 * j + 1], accB);
            accB = fmaf(fB[j].z, w[4 * j + 2], accB);
            accB = fmaf(fB[j].w, w[4 * j + 3], accB);
        }
        atomAddF32(gridc + (size_t)A.y * OC + lane, accA);
        if (hasB) atomAddF32(gridc + (size_t)B.y * OC + lane, accB);
    }
}

// 4 independent waves per block; lane = (h, c): half h covers o in
// [32h,32h+32). W2[kv] half-column in 32 VGPRs; halves via shfl_xor(32).
__global__ __launch_bounds__(256) void k_gather(const float* __restrict__ gridc,
                                                const float* __restrict__ W2,
                                                const int* __restrict__ rows,
                                                float* out) {
    const int kv = blockIdx.y;
    const int wid = threadIdx.x >> 6;
    const int lane = threadIdx.x & 63;
    const int h = lane >> 5;
    const int c = lane & 31;
    __shared__ int2 ls[4][VPW];

    float w[32];
#pragma unroll
    for (int j = 0; j < 32; ++j) w[j] = W2[(kv * OC + h * 32 + j) * IC + c];

    const int v0 = (blockIdx.x * 4 + wid) * VPW;
    const int n = (v0 < N_VOX)
                      ? compact_pairs(rows + kv * N_VOX, v0, lane, ls[wid])
                      : 0;

    for (int p = 0; p < n; p += 2) {
        const bool hasB = (p + 1 < n);
        const int2 A = ls[wid][p];
        const int2 B = ls[wid][hasB ? p + 1 : p];
        const float4* pA = (const float4*)(gridc + (size_t)A.y * OC + h * 32);
        const float4* pB = (const float4*)(gridc + (size_t)B.y * OC + h * 32);
        float4 gA[8], gB[8];
#pragma unroll
        for (int j = 0; j < 8; ++j) { gA[j] = pA[j]; gB[j] = pB[j]; }
        float accA = 0.f, accB = 0.f;
#pragma unroll
        for (int j = 0; j < 8; ++j) {
            accA = fmaf(gA[j].x, w[4 * j + 0], accA);
            accA = fmaf(gA[j].y, w[4 * j + 1], accA);
            accA = fmaf(gA[j].z, w[4 * j + 2], accA);
            accA = fmaf(gA[j].w, w[4 * j + 3], accA);
            accB = fmaf(gB[j].x, w[4 * j + 0], accB);
            accB = fmaf(gB[j].y, w[4 * j + 1], accB);
            accB = fmaf(gB[j].z, w[4 * j + 2], accB);
            accB = fmaf(gB[j].w, w[4 * j + 3], accB);
        }
        accA += __shfl_xor(accA, 32, 64);
        accB += __shfl_xor(accB, 32, 64);
        if (lane < 32) {
            atomAddF32(out + A.x * IC + c, accA);
            if (hasB) atomAddF32(out + B.x * IC + c, accB);
        }
    }
}

extern "C" void kernel_launch(void* const* d_in, const int* in_sizes, int n_in,
                              void* d_out, int out_size, void* d_ws, size_t ws_size,
                              hipStream_t stream) {
    const float* feat = (const float*)d_in[0];
    const int* coors = (const int*)d_in[1];
    const float* W1 = (const float*)d_in[2];
    const float* W2 = (const float*)d_in[3];
    float* out = (float*)d_out;

    if (ws_size < WS_NEEDED) return;  // loud failure: out stays zero

    char* ws = (char*)d_ws;
    int* keys = (int*)(ws + OFF_KEYS);
    int* vals = (int*)(ws + OFF_VALS);
    int* counter = (int*)(ws + OFF_CNT);
    int* rows = (int*)(ws + OFF_ROWS);
    float* gridc = (float*)(ws + OFF_GRID);

    k_init<<<dim3(15000), dim3(256), 0, stream>>>(keys, out, counter);
    k_build<<<dim3((N_VOX + 255) / 256), dim3(256), 0, stream>>>(coors, keys, rows);
    k_assign<<<dim3(TBL_SIZE / 2048), dim3(256), 0, stream>>>(keys, vals, counter,
                                                              (float4*)gridc);
    k_rows_fix<<<dim3((NKV * N_VOX + 255) / 256), dim3(256), 0, stream>>>(rows, vals);

    dim3 gs((N_VOX + VPBLK - 1) / VPBLK, NKV);
    k_scatter<<<gs, dim3(256), 0, stream>>>(feat, W1, rows, gridc);
    k_gather<<<gs, dim3(256), 0, stream>>>(gridc, W2, rows, out);
}